// Round 6
// baseline (105.734 us; speedup 1.0000x reference)
//
#include <hip/hip_runtime.h>
#include <math.h>

#define B_  2048
#define T_  200
#define D_  64
#define H1_ 80
#define H2_ 40

#define VSTR 72    // s_V row stride (bf16): 144 B rows -> ~2-way banks
#define WSTR 104   // W2T row stride (bf16)
#define HSTR 104   // h1 row stride (bf16); cols 80..95 zero pad

typedef __bf16 bf16x8 __attribute__((ext_vector_type(8)));
typedef float  f32x4  __attribute__((ext_vector_type(4)));

__device__ __forceinline__ float sigmoidf_(float x) {
    return __builtin_amdgcn_rcpf(1.0f + __expf(-x));
}

__global__ __launch_bounds__(256, 3)
void attn_din5(const float* __restrict__ query,
               const float* __restrict__ key,
               const int*   __restrict__ mask,
               const float* __restrict__ W1,
               const float* __restrict__ b1,
               const float* __restrict__ W2,
               const float* __restrict__ b2,
               const float* __restrict__ W3,
               const float* __restrict__ b3,
               float* __restrict__ out)
{
    __shared__ __bf16 s_V[H1_ * VSTR];       // 11520 B  V[h][f]
    __shared__ __bf16 s_W2T[48 * WSTR];      //  9984 B  W2T[g][h] zero-padded
    __shared__ __bf16 s_h1[4][16 * HSTR];    // 13312 B  per-wave h1 tile
    __shared__ float  s_q[D_];
    __shared__ float  s_bp[2][H1_];          // base partials
    __shared__ float  s_W3[48];
    __shared__ float  s_b2[48];
    __shared__ float  s_sc16[4][16];         // per-wave per-tile raw scores
    __shared__ float  s_red[8];
    __shared__ float  s_part[4][D_];
    // ~37.5 KB

    const int b    = blockIdx.x;
    const int tid  = threadIdx.x;
    const int lane = tid & 63;
    const int w    = tid >> 6;
    const int c16  = lane & 15;
    const int g16  = lane >> 4;

    const int   mv  = mask[b];
    const float b3v = b3[0];
    const float* kb = key + (size_t)b * T_ * D_;

    // ---------------- phase A: q, W3/b2, W2T ----------------
    if (tid < D_) s_q[tid] = query[b * D_ + tid];
    if (tid < 48) {
        s_W3[tid] = (tid < H2_) ? W3[tid] : 0.0f;
        s_b2[tid] = (tid < H2_) ? b2[tid] : 0.0f;
    }
    {
        int g = tid / WSTR, h = tid - g * WSTR;
        #pragma unroll
        for (int i = 0; i < 20; ++i) {
            int e = tid + 256 * i;
            if (e < 48 * WSTR) {
                float v = (g < H2_ && h < H1_) ? W2[h * H2_ + g] : 0.0f;
                s_W2T[g * WSTR + h] = (__bf16)v;
            }
            h += 48; g += 2;                  // 256 = 2*104 + 48
            if (h >= WSTR) { h -= WSTR; g += 1; }
        }
    }
    __syncthreads();

    // ---------------- phase B: collapsed weights V[h][f], base partials ----------------
    // din=[q,k,q-k,q*k] => pre1[t][h] = base[h] + sum_f k[t][f]*V[h][f]
    {
        int f = tid / H1_, h = tid - f * H1_;
        #pragma unroll
        for (int i = 0; i < 20; ++i) {        // 5120 exactly
            float v = W1[(64 + f) * H1_ + h] - W1[(128 + f) * H1_ + h]
                    + s_q[f] * W1[(192 + f) * H1_ + h];
            s_V[h * VSTR + f] = (__bf16)v;
            h += 16; f += 3;                  // 256 = 3*80 + 16
            if (h >= H1_) { h -= H1_; f += 1; }
        }
    }
    if (tid < 160) {
        int half = (tid >= 80) ? 1 : 0;
        int h = tid - half * 80;
        float a = half ? 0.0f : b1[h];
        const float* w1a = W1 + (half * 32) * H1_ + h;
        const float* w1c = W1 + (128 + half * 32) * H1_ + h;
        #pragma unroll 8
        for (int f = 0; f < 32; ++f)
            a = fmaf(s_q[half * 32 + f], w1a[f * H1_] + w1c[f * H1_], a);
        s_bp[half][h] = a;
    }
    // zero-fill h1 pad cols 80..95 once (own wave tile, never rewritten)
    {
        int row = lane & 15, c0 = 80 + (lane >> 4) * 4;
        *(uint2*)&s_h1[w][row * HSTR + c0] = make_uint2(0u, 0u);
    }
    __syncthreads();

    // ---------------- hoisted invariants ----------------
    float base_c[5], b2c[3];
    #pragma unroll
    for (int nt = 0; nt < 5; ++nt)
        base_c[nt] = s_bp[0][nt * 16 + c16] + s_bp[1][nt * 16 + c16];
    #pragma unroll
    for (int nt = 0; nt < 3; ++nt) b2c[nt] = s_b2[nt * 16 + c16];
    const float w3c0 = s_W3[c16], w3c1 = s_W3[16 + c16], w3c2 = s_W3[32 + c16];
    __bf16* myh = &s_h1[w][0];

    // ---------------- flash state ----------------
    float o00,o01,o02,o03,o04,o05,o06,o07,o08,o09,o10,o11,o12,o13,o14,o15;
    o00=o01=o02=o03=o04=o05=o06=o07=o08=o09=o10=o11=o12=o13=o14=o15=0.0f;
    float m_run = -1e30f, l_run = 0.0f;

    // prologue: load first tile's key rows (f32, kept for o-accumulation)
    float4 u0, u1, u2, u3;
    {
        int tr = w * 16 + c16;
        const float* kr = kb + (size_t)((tr < T_) ? tr : (T_ - 1)) * D_ + g16 * 8;
        u0 = *(const float4*)(kr);
        u1 = *(const float4*)(kr + 4);
        u2 = *(const float4*)(kr + 32);
        u3 = *(const float4*)(kr + 36);
    }

    // ---------------- main loop: wave-independent tiles, barrier-free ----------------
    for (int tt = w; tt < 13; tt += 4) {
        // prefetch next tile (T14: issue before compute)
        float4 n0 = u0, n1 = u1, n2 = u2, n3 = u3;
        const int ttn = tt + 4;
        if (ttn < 13) {
            int tr = ttn * 16 + c16;
            const float* kr = kb + (size_t)((tr < T_) ? tr : (T_ - 1)) * D_ + g16 * 8;
            n0 = *(const float4*)(kr);
            n1 = *(const float4*)(kr + 4);
            n2 = *(const float4*)(kr + 32);
            n3 = *(const float4*)(kr + 36);
        }

        bf16x8 af0, af1;
        af0[0] = (__bf16)u0.x; af0[1] = (__bf16)u0.y; af0[2] = (__bf16)u0.z; af0[3] = (__bf16)u0.w;
        af0[4] = (__bf16)u1.x; af0[5] = (__bf16)u1.y; af0[6] = (__bf16)u1.z; af0[7] = (__bf16)u1.w;
        af1[0] = (__bf16)u2.x; af1[1] = (__bf16)u2.y; af1[2] = (__bf16)u2.z; af1[3] = (__bf16)u2.w;
        af1[4] = (__bf16)u3.x; af1[5] = (__bf16)u3.y; af1[6] = (__bf16)u3.z; af1[7] = (__bf16)u3.w;

        // layer 1 -> sigmoid -> h1 (own-wave LDS transpose)
        #pragma unroll
        for (int nt = 0; nt < 5; ++nt) {
            float bb = base_c[nt];
            f32x4 c = { bb, bb, bb, bb };
            bf16x8 bv0 = *(const bf16x8*)&s_V[(nt * 16 + c16) * VSTR + g16 * 8];
            bf16x8 bv1 = *(const bf16x8*)&s_V[(nt * 16 + c16) * VSTR + 32 + g16 * 8];
            c = __builtin_amdgcn_mfma_f32_16x16x32_bf16(af0, bv0, c, 0, 0, 0);
            c = __builtin_amdgcn_mfma_f32_16x16x32_bf16(af1, bv1, c, 0, 0, 0);
            #pragma unroll
            for (int r = 0; r < 4; ++r)
                myh[(g16 * 4 + r) * HSTR + nt * 16 + c16] = (__bf16)sigmoidf_(c[r]);
        }

        // layer 2 (k=0..95 incl. zero pad)
        bf16x8 a2_0 = *(const bf16x8*)&myh[c16 * HSTR + g16 * 8];
        bf16x8 a2_1 = *(const bf16x8*)&myh[c16 * HSTR + 32 + g16 * 8];
        bf16x8 a2_2 = *(const bf16x8*)&myh[c16 * HSTR + 64 + g16 * 8];
        f32x4 acc2[3];
        #pragma unroll
        for (int nt = 0; nt < 3; ++nt) {
            float bb = b2c[nt];
            f32x4 c = { bb, bb, bb, bb };
            bf16x8 w0 = *(const bf16x8*)&s_W2T[(nt * 16 + c16) * WSTR + g16 * 8];
            bf16x8 w1 = *(const bf16x8*)&s_W2T[(nt * 16 + c16) * WSTR + 32 + g16 * 8];
            bf16x8 w2 = *(const bf16x8*)&s_W2T[(nt * 16 + c16) * WSTR + 64 + g16 * 8];
            c = __builtin_amdgcn_mfma_f32_16x16x32_bf16(a2_0, w0, c, 0, 0, 0);
            c = __builtin_amdgcn_mfma_f32_16x16x32_bf16(a2_1, w1, c, 0, 0, 0);
            c = __builtin_amdgcn_mfma_f32_16x16x32_bf16(a2_2, w2, c, 0, 0, 0);
            acc2[nt] = c;
        }

        // layer 3: reduce 40 g's (spread over c16) -> raw masked score to s_sc16
        const int tb = tt * 16;
        #pragma unroll
        for (int r = 0; r < 4; ++r) {
            float partial = sigmoidf_(acc2[0][r]) * w3c0
                          + sigmoidf_(acc2[1][r]) * w3c1
                          + sigmoidf_(acc2[2][r]) * w3c2;
            partial += __shfl_xor(partial, 1);
            partial += __shfl_xor(partial, 2);
            partial += __shfl_xor(partial, 4);
            partial += __shfl_xor(partial, 8);
            if (c16 == 0) {
                int t = tb + g16 * 4 + r;
                s_sc16[w][g16 * 4 + r] = (t < mv) ? (partial + b3v) * 0.125f : -1e30f;
            }
        }

        // online softmax update (all 64 lanes; lane's row t = tb + c16)
        float s = s_sc16[w][c16];
        float tm = s;
        tm = fmaxf(tm, __shfl_xor(tm, 1));
        tm = fmaxf(tm, __shfl_xor(tm, 2));
        tm = fmaxf(tm, __shfl_xor(tm, 4));
        tm = fmaxf(tm, __shfl_xor(tm, 8));
        float m_new = fmaxf(m_run, tm);
        float alpha = __expf(m_run - m_new);
        float p = __expf(s - m_new);          // 0 for masked rows once m_new is real
        float psum = p;
        psum += __shfl_xor(psum, 1);
        psum += __shfl_xor(psum, 2);
        psum += __shfl_xor(psum, 4);
        psum += __shfl_xor(psum, 8);
        l_run = l_run * alpha + psum;
        o00 = o00 * alpha + p * u0.x;  o01 = o01 * alpha + p * u0.y;
        o02 = o02 * alpha + p * u0.z;  o03 = o03 * alpha + p * u0.w;
        o04 = o04 * alpha + p * u1.x;  o05 = o05 * alpha + p * u1.y;
        o06 = o06 * alpha + p * u1.z;  o07 = o07 * alpha + p * u1.w;
        o08 = o08 * alpha + p * u2.x;  o09 = o09 * alpha + p * u2.y;
        o10 = o10 * alpha + p * u2.z;  o11 = o11 * alpha + p * u2.w;
        o12 = o12 * alpha + p * u3.x;  o13 = o13 * alpha + p * u3.y;
        o14 = o14 * alpha + p * u3.z;  o15 = o15 * alpha + p * u3.w;
        m_run = m_new;

        u0 = n0; u1 = n1; u2 = n2; u3 = n3;
    }

    // ---------------- cross-wave merge: (m_w, l_w, o_w) ----------------
    if (lane == 0) { s_red[w] = m_run; s_red[4 + w] = l_run; }
    __syncthreads();
    float mM = fmaxf(fmaxf(s_red[0], s_red[1]), fmaxf(s_red[2], s_red[3]));
    float fw = __expf(m_run - mM);            // wave-uniform
    float tot = __expf(s_red[0] - mM) * s_red[4] + __expf(s_red[1] - mM) * s_red[5]
              + __expf(s_red[2] - mM) * s_red[6] + __expf(s_red[3] - mM) * s_red[7];
    float inv_total = __builtin_amdgcn_rcpf(tot);

    // reduce o over the 16 c16-lanes, write scaled partials
    #define ORED(X) X += __shfl_xor(X,1); X += __shfl_xor(X,2); X += __shfl_xor(X,4); X += __shfl_xor(X,8);
    ORED(o00) ORED(o01) ORED(o02) ORED(o03) ORED(o04) ORED(o05) ORED(o06) ORED(o07)
    ORED(o08) ORED(o09) ORED(o10) ORED(o11) ORED(o12) ORED(o13) ORED(o14) ORED(o15)
    #undef ORED
    if (c16 == 0) {
        float* sp = &s_part[w][0];
        sp[g16 * 8 + 0] = o00 * fw;  sp[g16 * 8 + 1] = o01 * fw;
        sp[g16 * 8 + 2] = o02 * fw;  sp[g16 * 8 + 3] = o03 * fw;
        sp[g16 * 8 + 4] = o04 * fw;  sp[g16 * 8 + 5] = o05 * fw;
        sp[g16 * 8 + 6] = o06 * fw;  sp[g16 * 8 + 7] = o07 * fw;
        sp[32 + g16 * 8 + 0] = o08 * fw;  sp[32 + g16 * 8 + 1] = o09 * fw;
        sp[32 + g16 * 8 + 2] = o10 * fw;  sp[32 + g16 * 8 + 3] = o11 * fw;
        sp[32 + g16 * 8 + 4] = o12 * fw;  sp[32 + g16 * 8 + 5] = o13 * fw;
        sp[32 + g16 * 8 + 6] = o14 * fw;  sp[32 + g16 * 8 + 7] = o15 * fw;
    }
    __syncthreads();
    if (tid < D_) {
        float r = (s_part[0][tid] + s_part[1][tid] + s_part[2][tid] + s_part[3][tid]) * inv_total;
        out[b * D_ + tid] = r;
    }
}

extern "C" void kernel_launch(void* const* d_in, const int* in_sizes, int n_in,
                              void* d_out, int out_size, void* d_ws, size_t ws_size,
                              hipStream_t stream)
{
    const float* query = (const float*)d_in[0];
    const float* key   = (const float*)d_in[1];
    const int*   mask  = (const int*)  d_in[2];
    const float* W1    = (const float*)d_in[3];
    const float* b1    = (const float*)d_in[4];
    const float* W2    = (const float*)d_in[5];
    const float* b2    = (const float*)d_in[6];
    const float* W3    = (const float*)d_in[7];
    const float* b3    = (const float*)d_in[8];
    float* out = (float*)d_out;

    attn_din5<<<B_, 256, 0, stream>>>(query, key, mask, W1, b1, W2, b2, W3, b3, out);
}

// Round 7
// 66.389 us; speedup vs baseline: 1.5926x; 1.5926x over previous
//
#include <hip/hip_runtime.h>
#include <math.h>

#define B_  2048
#define T_  200
#define D_  64
#define H1_ 80
#define H2_ 40

#define VSTR 72    // s_V row stride (bf16): 144 B rows -> ~2-way banks
#define WSTR 104   // W2T row stride (bf16)
#define HSTR 104   // h1 row stride (bf16); cols 80..95 zero pad

typedef __bf16 bf16x8 __attribute__((ext_vector_type(8)));
typedef float  f32x4  __attribute__((ext_vector_type(4)));

__device__ __forceinline__ float sigmoidf_(float x) {
    return __builtin_amdgcn_rcpf(1.0f + __expf(-x));
}

__global__ __launch_bounds__(256, 3)
void attn_din7(const float* __restrict__ query,
               const float* __restrict__ key,
               const int*   __restrict__ mask,
               const float* __restrict__ W1,
               const float* __restrict__ b1,
               const float* __restrict__ W2,
               const float* __restrict__ b2,
               const float* __restrict__ W3,
               const float* __restrict__ b3,
               float* __restrict__ out)
{
    __shared__ __bf16 s_V[H1_ * VSTR];       // 11520 B  V[h][f]
    __shared__ __bf16 s_W2T[48 * WSTR];      //  9984 B  W2T[g][h] zero-padded
    __shared__ __bf16 s_h1[4][16 * HSTR];    // 13312 B  per-wave h1 tile
    __shared__ float  s_q[D_];
    __shared__ float  s_bp[2][H1_];          // base partials
    __shared__ float  s_W3[48];
    __shared__ float  s_b2[48];
    __shared__ float  s_scf[256];
    __shared__ float  s_red[8];
    // ~37.3 KB -> LDS allows 4 blocks/CU; regs cap at 3

    const int b    = blockIdx.x;
    const int tid  = threadIdx.x;
    const int lane = tid & 63;
    const int w    = tid >> 6;
    const int c16  = lane & 15;
    const int g16  = lane >> 4;

    const int   mv  = mask[b];
    const float b3v = b3[0];
    const float* kb = key + (size_t)b * T_ * D_;

    // ---------------- phase A: q, W3/b2, W2T ----------------
    if (tid < D_) s_q[tid] = query[b * D_ + tid];
    if (tid < 48) {
        s_W3[tid] = (tid < H2_) ? W3[tid] : 0.0f;
        s_b2[tid] = (tid < H2_) ? b2[tid] : 0.0f;
    }
    {
        int g = tid / WSTR, h = tid - g * WSTR;
        #pragma unroll
        for (int i = 0; i < 20; ++i) {
            int e = tid + 256 * i;
            if (e < 48 * WSTR) {
                float v = (g < H2_ && h < H1_) ? W2[h * H2_ + g] : 0.0f;
                s_W2T[g * WSTR + h] = (__bf16)v;
            }
            h += 48; g += 2;                  // 256 = 2*104 + 48
            if (h >= WSTR) { h -= WSTR; g += 1; }
        }
    }
    s_scf[tid] = -1e30f;
    __syncthreads();

    // ---------------- phase B: collapsed weights V[h][f], base partials ----------------
    // din=[q,k,q-k,q*k] => pre1[t][h] = base[h] + sum_f k[t][f]*V[h][f]
    {
        int f = tid / H1_, h = tid - f * H1_;
        #pragma unroll
        for (int i = 0; i < 20; ++i) {        // 5120 exactly
            float v = W1[(64 + f) * H1_ + h] - W1[(128 + f) * H1_ + h]
                    + s_q[f] * W1[(192 + f) * H1_ + h];
            s_V[h * VSTR + f] = (__bf16)v;
            h += 16; f += 3;                  // 256 = 3*80 + 16
            if (h >= H1_) { h -= H1_; f += 1; }
        }
    }
    if (tid < 160) {
        int half = (tid >= 80) ? 1 : 0;
        int h = tid - half * 80;
        float a = half ? 0.0f : b1[h];
        const float* w1a = W1 + (half * 32) * H1_ + h;
        const float* w1c = W1 + (128 + half * 32) * H1_ + h;
        #pragma unroll 8
        for (int f = 0; f < 32; ++f)
            a = fmaf(s_q[half * 32 + f], w1a[f * H1_] + w1c[f * H1_], a);
        s_bp[half][h] = a;
    }
    // zero-fill h1 pad cols 80..95 once (own wave tile, never rewritten)
    {
        int row = lane & 15, c0 = 80 + (lane >> 4) * 4;
        *(uint2*)&s_h1[w][row * HSTR + c0] = make_uint2(0u, 0u);
    }
    __syncthreads();

    // ---------------- hoisted invariants ----------------
    float base_c[5], b2c[3];
    #pragma unroll
    for (int nt = 0; nt < 5; ++nt)
        base_c[nt] = s_bp[0][nt * 16 + c16] + s_bp[1][nt * 16 + c16];
    #pragma unroll
    for (int nt = 0; nt < 3; ++nt) b2c[nt] = s_b2[nt * 16 + c16];
    const float w3c0 = s_W3[c16], w3c1 = s_W3[16 + c16], w3c2 = s_W3[32 + c16];
    __bf16* myh = &s_h1[w][0];

    // prologue: load first tile's key rows
    float4 u0, u1, u2, u3;
    {
        int tr = w * 16 + c16;
        const float* kr = kb + (size_t)((tr < T_) ? tr : (T_ - 1)) * D_ + g16 * 8;
        u0 = *(const float4*)(kr);
        u1 = *(const float4*)(kr + 4);
        u2 = *(const float4*)(kr + 32);
        u3 = *(const float4*)(kr + 36);
    }

    // ---------------- main loop: wave-independent tiles, barrier-free ----------------
    for (int tt = w; tt < 13; tt += 4) {
        // convert current tile to bf16 A-frags, freeing u for prefetch overwrite
        bf16x8 af0, af1;
        af0[0] = (__bf16)u0.x; af0[1] = (__bf16)u0.y; af0[2] = (__bf16)u0.z; af0[3] = (__bf16)u0.w;
        af0[4] = (__bf16)u1.x; af0[5] = (__bf16)u1.y; af0[6] = (__bf16)u1.z; af0[7] = (__bf16)u1.w;
        af1[0] = (__bf16)u2.x; af1[1] = (__bf16)u2.y; af1[2] = (__bf16)u2.z; af1[3] = (__bf16)u2.w;
        af1[4] = (__bf16)u3.x; af1[5] = (__bf16)u3.y; af1[6] = (__bf16)u3.z; af1[7] = (__bf16)u3.w;

        // T14 prefetch: issue next tile's loads now; latency hides under this tile's MLP
        const int ttn = tt + 4;
        if (ttn < 13) {
            int tr = ttn * 16 + c16;
            const float* kr = kb + (size_t)((tr < T_) ? tr : (T_ - 1)) * D_ + g16 * 8;
            u0 = *(const float4*)(kr);
            u1 = *(const float4*)(kr + 4);
            u2 = *(const float4*)(kr + 32);
            u3 = *(const float4*)(kr + 36);
        }

        // layer 1 -> sigmoid -> h1 (own-wave LDS transpose), acc streamed per nt
        #pragma unroll
        for (int nt = 0; nt < 5; ++nt) {
            float bb = base_c[nt];
            f32x4 c = { bb, bb, bb, bb };
            bf16x8 bv0 = *(const bf16x8*)&s_V[(nt * 16 + c16) * VSTR + g16 * 8];
            bf16x8 bv1 = *(const bf16x8*)&s_V[(nt * 16 + c16) * VSTR + 32 + g16 * 8];
            c = __builtin_amdgcn_mfma_f32_16x16x32_bf16(af0, bv0, c, 0, 0, 0);
            c = __builtin_amdgcn_mfma_f32_16x16x32_bf16(af1, bv1, c, 0, 0, 0);
            #pragma unroll
            for (int r = 0; r < 4; ++r)
                myh[(g16 * 4 + r) * HSTR + nt * 16 + c16] = (__bf16)sigmoidf_(c[r]);
        }

        // layer 2 (k=0..95 incl. zero pad)
        bf16x8 a2_0 = *(const bf16x8*)&myh[c16 * HSTR + g16 * 8];
        bf16x8 a2_1 = *(const bf16x8*)&myh[c16 * HSTR + 32 + g16 * 8];
        bf16x8 a2_2 = *(const bf16x8*)&myh[c16 * HSTR + 64 + g16 * 8];
        f32x4 acc2[3];
        #pragma unroll
        for (int nt = 0; nt < 3; ++nt) {
            float bb = b2c[nt];
            f32x4 c = { bb, bb, bb, bb };
            bf16x8 w0 = *(const bf16x8*)&s_W2T[(nt * 16 + c16) * WSTR + g16 * 8];
            bf16x8 w1 = *(const bf16x8*)&s_W2T[(nt * 16 + c16) * WSTR + 32 + g16 * 8];
            bf16x8 w2 = *(const bf16x8*)&s_W2T[(nt * 16 + c16) * WSTR + 64 + g16 * 8];
            c = __builtin_amdgcn_mfma_f32_16x16x32_bf16(a2_0, w0, c, 0, 0, 0);
            c = __builtin_amdgcn_mfma_f32_16x16x32_bf16(a2_1, w1, c, 0, 0, 0);
            c = __builtin_amdgcn_mfma_f32_16x16x32_bf16(a2_2, w2, c, 0, 0, 0);
            acc2[nt] = c;
        }

        // layer 3 + masked score
        const int tb = tt * 16;
        #pragma unroll
        for (int r = 0; r < 4; ++r) {
            float partial = sigmoidf_(acc2[0][r]) * w3c0
                          + sigmoidf_(acc2[1][r]) * w3c1
                          + sigmoidf_(acc2[2][r]) * w3c2;
            partial += __shfl_xor(partial, 1);
            partial += __shfl_xor(partial, 2);
            partial += __shfl_xor(partial, 4);
            partial += __shfl_xor(partial, 8);
            int t = tb + g16 * 4 + r;
            if (c16 == 0 && t < mv)
                s_scf[t] = (partial + b3v) * 0.125f;   // / sqrt(64); masked stay -1e30
        }
    }
    __syncthreads();

    // ---------------- softmax over 256 slots ----------------
    float score = s_scf[tid];
    float v = score;
    #pragma unroll
    for (int off = 32; off >= 1; off >>= 1) v = fmaxf(v, __shfl_xor(v, off));
    if (lane == 0) s_red[w] = v;
    __syncthreads();
    float m = fmaxf(fmaxf(s_red[0], s_red[1]), fmaxf(s_red[2], s_red[3]));
    float pexp = __expf(score - m);
    float ps = pexp;
    #pragma unroll
    for (int off = 32; off >= 1; off >>= 1) ps += __shfl_xor(ps, off);
    if (lane == 0) s_red[4 + w] = ps;
    s_scf[tid] = pexp;
    __syncthreads();
    float inv_total = __builtin_amdgcn_rcpf(s_red[4] + s_red[5] + s_red[6] + s_red[7]);

    // ---------------- weighted sum: out[b][d] = sum_t p[t]*key[b][t][d] (L2/L3-served) ----------------
    float* s_part = (float*)&s_h1[0][0];    // h1 dead now
    float acc = 0.0f;
    #pragma unroll 10
    for (int t = w * 50; t < w * 50 + 50; ++t)
        acc = fmaf(s_scf[t], kb[t * D_ + lane], acc);
    s_part[w * 64 + lane] = acc;
    __syncthreads();
    if (tid < D_) {
        float r = (s_part[0 * 64 + tid] + s_part[1 * 64 + tid] +
                   s_part[2 * 64 + tid] + s_part[3 * 64 + tid]) * inv_total;
        out[b * D_ + tid] = r;
    }
}

extern "C" void kernel_launch(void* const* d_in, const int* in_sizes, int n_in,
                              void* d_out, int out_size, void* d_ws, size_t ws_size,
                              hipStream_t stream)
{
    const float* query = (const float*)d_in[0];
    const float* key   = (const float*)d_in[1];
    const int*   mask  = (const int*)  d_in[2];
    const float* W1    = (const float*)d_in[3];
    const float* b1    = (const float*)d_in[4];
    const float* W2    = (const float*)d_in[5];
    const float* b2    = (const float*)d_in[6];
    const float* W3    = (const float*)d_in[7];
    const float* b3    = (const float*)d_in[8];
    float* out = (float*)d_out;

    attn_din7<<<B_, 256, 0, stream>>>(query, key, mask, W1, b1, W2, b2, W3, b3, out);
}

// Round 8
// 56.153 us; speedup vs baseline: 1.8830x; 1.1823x over previous
//
#include <hip/hip_runtime.h>
#include <math.h>

#define B_  2048
#define T_  200
#define D_  64
#define H1_ 80
#define H2_ 40

#define VSTR 72    // s_V row stride (bf16): 144 B rows
#define WSTR 104   // W2T row stride (bf16)
#define HSTR 104   // h1 row stride (bf16); cols 80..95 zero pad

// d_ws layout (bytes):
#define WS_A    0        // A[h][f]  bf16 [80][64] = 10240
#define WS_C    10240    // C[h][f]  bf16 [80][64] = 10240
#define WS_W2T  20480    // W2Tp[g][h] bf16 [48][104] = 9984
#define WS_ACT  30464    // W1acT[h][f] f32 [80][64] = 20480  (16B aligned)

typedef __bf16 bf16x8 __attribute__((ext_vector_type(8)));
typedef float  f32x4  __attribute__((ext_vector_type(4)));

__device__ __forceinline__ float sigmoidf_(float x) {
    return __builtin_amdgcn_rcpf(1.0f + __expf(-x));
}

// ---------- prep: block-invariant weight transforms (runs once per call) ----------
__global__ __launch_bounds__(256)
void prep_kernel(const float* __restrict__ W1, const float* __restrict__ W2,
                 void* __restrict__ ws)
{
    __bf16* A    = (__bf16*)((char*)ws + WS_A);
    __bf16* C    = (__bf16*)((char*)ws + WS_C);
    __bf16* W2Tp = (__bf16*)((char*)ws + WS_W2T);
    float*  acT  = (float*)((char*)ws + WS_ACT);
    const int e0 = blockIdx.x * 256 + threadIdx.x;

    for (int e = e0; e < H1_ * D_; e += 2048) {     // 5120: A, C, W1acT
        int h = e >> 6, f = e & 63;
        float wb = W1[(64  + f) * H1_ + h];
        float wc = W1[(128 + f) * H1_ + h];
        float wd = W1[(192 + f) * H1_ + h];
        float wa = W1[f * H1_ + h];
        A[e]   = (__bf16)(wb - wc);
        C[e]   = (__bf16)wd;
        acT[e] = wa + wc;
    }
    for (int e = e0; e < 48 * WSTR; e += 2048) {    // 4992: padded W2^T
        int g = e / WSTR, h = e - g * WSTR;
        W2Tp[e] = (g < H2_ && h < H1_) ? (__bf16)W2[h * H2_ + g] : (__bf16)0.0f;
    }
}

// ---------- main ----------
__global__ __launch_bounds__(256, 3)
void attn_din8(const float* __restrict__ query,
               const float* __restrict__ key,
               const int*   __restrict__ mask,
               const float* __restrict__ b1,
               const float* __restrict__ b2,
               const float* __restrict__ W3,
               const float* __restrict__ b3,
               const void*  __restrict__ ws,
               float* __restrict__ out)
{
    __shared__ __align__(16) __bf16 s_V[H1_ * VSTR];       // 11520 B  V[h][f]
    __shared__ __align__(16) __bf16 s_W2T[48 * WSTR];      //  9984 B
    __shared__ __align__(16) __bf16 s_h1[4][16 * HSTR];    // 13312 B  per-wave h1
    __shared__ float  s_q[D_];
    __shared__ float  s_bp[2][H1_];
    __shared__ float  s_W3[48];
    __shared__ float  s_b2[48];
    __shared__ float  s_scf[256];
    __shared__ float  s_red[8];
    // ~37.3 KB

    const int b    = blockIdx.x;
    const int tid  = threadIdx.x;
    const int lane = tid & 63;
    const int w    = tid >> 6;
    const int c16  = lane & 15;
    const int g16  = lane >> 4;

    const int   mv  = mask[b];
    const int   ntiles = (mv + 15) >> 4;    // tiles with any unmasked row
    const float b3v = b3[0];
    const float* kb = key + (size_t)b * T_ * D_;

    const __bf16* wsA   = (const __bf16*)((const char*)ws + WS_A);
    const __bf16* wsC   = (const __bf16*)((const char*)ws + WS_C);
    const uint4*  wsW2T = (const uint4*) ((const char*)ws + WS_W2T);
    const float*  wsacT = (const float*) ((const char*)ws + WS_ACT);

    // ---------------- phase A: q, W3/b2, W2T copy ----------------
    if (tid < D_) s_q[tid] = query[b * D_ + tid];
    if (tid < 48) {
        s_W3[tid] = (tid < H2_) ? W3[tid] : 0.0f;
        s_b2[tid] = (tid < H2_) ? b2[tid] : 0.0f;
    }
    s_scf[tid] = -1e30f;
    {
        uint4* dst = (uint4*)s_W2T;                 // 624 16B chunks
        #pragma unroll
        for (int i = 0; i < 3; ++i) {
            int e = tid + 256 * i;
            if (e < 624) dst[e] = wsW2T[e];
        }
    }
    __syncthreads();

    // ---------------- phase B: V = A + q*C (bf16x8 chunks), base partials ----------------
    #pragma unroll
    for (int i = 0; i < 3; ++i) {
        int e = tid + 256 * i;                      // 640 chunks of 8
        if (e < 640) {
            int h = e >> 3, f8 = e & 7;
            bf16x8 a8 = *(const bf16x8*)&wsA[e * 8];
            bf16x8 c8 = *(const bf16x8*)&wsC[e * 8];
            bf16x8 v8;
            #pragma unroll
            for (int j = 0; j < 8; ++j)
                v8[j] = (__bf16)((float)a8[j] + s_q[f8 * 8 + j] * (float)c8[j]);
            *(bf16x8*)&s_V[h * VSTR + f8 * 8] = v8;
        }
    }
    if (tid < 160) {
        int half = (tid >= 80) ? 1 : 0;
        int h = tid - half * 80;
        float a = half ? 0.0f : b1[h];
        const f32x4* row = (const f32x4*)&wsacT[h * D_ + half * 32];
        #pragma unroll
        for (int f4 = 0; f4 < 8; ++f4) {
            f32x4 v = row[f4];
            a = fmaf(s_q[half * 32 + f4 * 4 + 0], v[0], a);
            a = fmaf(s_q[half * 32 + f4 * 4 + 1], v[1], a);
            a = fmaf(s_q[half * 32 + f4 * 4 + 2], v[2], a);
            a = fmaf(s_q[half * 32 + f4 * 4 + 3], v[3], a);
        }
        s_bp[half][h] = a;
    }
    // zero h1 pad cols 80..95 once (own-wave tile, never rewritten)
    {
        int row = lane & 15, c0 = 80 + (lane >> 4) * 4;
        *(uint2*)&s_h1[w][row * HSTR + c0] = make_uint2(0u, 0u);
    }
    __syncthreads();

    // ---------------- hoisted invariants ----------------
    float base_c[5], b2c[3];
    #pragma unroll
    for (int nt = 0; nt < 5; ++nt)
        base_c[nt] = s_bp[0][nt * 16 + c16] + s_bp[1][nt * 16 + c16];
    #pragma unroll
    for (int nt = 0; nt < 3; ++nt) b2c[nt] = s_b2[nt * 16 + c16];
    const float w3c0 = s_W3[c16], w3c1 = s_W3[16 + c16], w3c2 = s_W3[32 + c16];
    __bf16* myh = &s_h1[w][0];

    // prologue: first live tile's key rows
    float4 u0, u1, u2, u3;
    if (w < ntiles) {
        int tr = w * 16 + c16;
        const float* kr = kb + (size_t)((tr < T_) ? tr : (T_ - 1)) * D_ + g16 * 8;
        u0 = *(const float4*)(kr);
        u1 = *(const float4*)(kr + 4);
        u2 = *(const float4*)(kr + 32);
        u3 = *(const float4*)(kr + 36);
    }

    // ---------------- main loop: only tiles with t < mv ----------------
    for (int tt = w; tt < ntiles; tt += 4) {
        bf16x8 af0, af1;
        af0[0] = (__bf16)u0.x; af0[1] = (__bf16)u0.y; af0[2] = (__bf16)u0.z; af0[3] = (__bf16)u0.w;
        af0[4] = (__bf16)u1.x; af0[5] = (__bf16)u1.y; af0[6] = (__bf16)u1.z; af0[7] = (__bf16)u1.w;
        af1[0] = (__bf16)u2.x; af1[1] = (__bf16)u2.y; af1[2] = (__bf16)u2.z; af1[3] = (__bf16)u2.w;
        af1[4] = (__bf16)u3.x; af1[5] = (__bf16)u3.y; af1[6] = (__bf16)u3.z; af1[7] = (__bf16)u3.w;

        const int ttn = tt + 4;                 // T14 prefetch
        if (ttn < ntiles) {
            int tr = ttn * 16 + c16;
            const float* kr = kb + (size_t)((tr < T_) ? tr : (T_ - 1)) * D_ + g16 * 8;
            u0 = *(const float4*)(kr);
            u1 = *(const float4*)(kr + 4);
            u2 = *(const float4*)(kr + 32);
            u3 = *(const float4*)(kr + 36);
        }

        // layer 1 -> sigmoid -> h1 (own-wave LDS transpose)
        #pragma unroll
        for (int nt = 0; nt < 5; ++nt) {
            float bb = base_c[nt];
            f32x4 c = { bb, bb, bb, bb };
            bf16x8 bv0 = *(const bf16x8*)&s_V[(nt * 16 + c16) * VSTR + g16 * 8];
            bf16x8 bv1 = *(const bf16x8*)&s_V[(nt * 16 + c16) * VSTR + 32 + g16 * 8];
            c = __builtin_amdgcn_mfma_f32_16x16x32_bf16(af0, bv0, c, 0, 0, 0);
            c = __builtin_amdgcn_mfma_f32_16x16x32_bf16(af1, bv1, c, 0, 0, 0);
            #pragma unroll
            for (int r = 0; r < 4; ++r)
                myh[(g16 * 4 + r) * HSTR + nt * 16 + c16] = (__bf16)sigmoidf_(c[r]);
        }

        // layer 2
        bf16x8 a2_0 = *(const bf16x8*)&myh[c16 * HSTR + g16 * 8];
        bf16x8 a2_1 = *(const bf16x8*)&myh[c16 * HSTR + 32 + g16 * 8];
        bf16x8 a2_2 = *(const bf16x8*)&myh[c16 * HSTR + 64 + g16 * 8];
        f32x4 acc2[3];
        #pragma unroll
        for (int nt = 0; nt < 3; ++nt) {
            float bb = b2c[nt];
            f32x4 c = { bb, bb, bb, bb };
            bf16x8 w0 = *(const bf16x8*)&s_W2T[(nt * 16 + c16) * WSTR + g16 * 8];
            bf16x8 w1 = *(const bf16x8*)&s_W2T[(nt * 16 + c16) * WSTR + 32 + g16 * 8];
            bf16x8 w2 = *(const bf16x8*)&s_W2T[(nt * 16 + c16) * WSTR + 64 + g16 * 8];
            c = __builtin_amdgcn_mfma_f32_16x16x32_bf16(a2_0, w0, c, 0, 0, 0);
            c = __builtin_amdgcn_mfma_f32_16x16x32_bf16(a2_1, w1, c, 0, 0, 0);
            c = __builtin_amdgcn_mfma_f32_16x16x32_bf16(a2_2, w2, c, 0, 0, 0);
            acc2[nt] = c;
        }

        // layer 3 + masked score
        const int tb = tt * 16;
        #pragma unroll
        for (int r = 0; r < 4; ++r) {
            float partial = sigmoidf_(acc2[0][r]) * w3c0
                          + sigmoidf_(acc2[1][r]) * w3c1
                          + sigmoidf_(acc2[2][r]) * w3c2;
            partial += __shfl_xor(partial, 1);
            partial += __shfl_xor(partial, 2);
            partial += __shfl_xor(partial, 4);
            partial += __shfl_xor(partial, 8);
            int t = tb + g16 * 4 + r;
            if (c16 == 0 && t < mv)
                s_scf[t] = (partial + b3v) * 0.125f;
        }
    }
    __syncthreads();

    // ---------------- softmax over 256 slots (masked stay -1e30 -> p=0) ----------------
    float score = s_scf[tid];
    float v = score;
    #pragma unroll
    for (int off = 32; off >= 1; off >>= 1) v = fmaxf(v, __shfl_xor(v, off));
    if (lane == 0) s_red[w] = v;
    __syncthreads();
    float m = fmaxf(fmaxf(s_red[0], s_red[1]), fmaxf(s_red[2], s_red[3]));
    float pexp = __expf(score - m);
    float ps = pexp;
    #pragma unroll
    for (int off = 32; off >= 1; off >>= 1) ps += __shfl_xor(ps, off);
    if (lane == 0) s_red[4 + w] = ps;
    s_scf[tid] = pexp;
    __syncthreads();
    float inv_total = __builtin_amdgcn_rcpf(s_red[4] + s_red[5] + s_red[6] + s_red[7]);

    // ---------------- weighted sum over t < mv only ----------------
    float* s_part = (float*)&s_h1[0][0];
    float acc = 0.0f;
    for (int t = w; t < mv; t += 4)
        acc = fmaf(s_scf[t], kb[t * D_ + lane], acc);
    s_part[w * 64 + lane] = acc;
    __syncthreads();
    if (tid < D_) {
        float r = (s_part[0 * 64 + tid] + s_part[1 * 64 + tid] +
                   s_part[2 * 64 + tid] + s_part[3 * 64 + tid]) * inv_total;
        out[b * D_ + tid] = r;
    }
}

extern "C" void kernel_launch(void* const* d_in, const int* in_sizes, int n_in,
                              void* d_out, int out_size, void* d_ws, size_t ws_size,
                              hipStream_t stream)
{
    const float* query = (const float*)d_in[0];
    const float* key   = (const float*)d_in[1];
    const int*   mask  = (const int*)  d_in[2];
    const float* W1    = (const float*)d_in[3];
    const float* b1    = (const float*)d_in[4];
    const float* W2    = (const float*)d_in[5];
    const float* b2    = (const float*)d_in[6];
    const float* W3    = (const float*)d_in[7];
    const float* b3    = (const float*)d_in[8];
    float* out = (float*)d_out;

    prep_kernel<<<8, 256, 0, stream>>>(W1, W2, d_ws);
    attn_din8<<<B_, 256, 0, stream>>>(query, key, mask, b1, b2, W3, b3, d_ws, out);
}

// Round 9
// 47.492 us; speedup vs baseline: 2.2263x; 1.1824x over previous
//
#include <hip/hip_runtime.h>
#include <math.h>

#define B_  2048
#define T_  200
#define D_  64
#define H1_ 80
#define H2_ 40

#define VSTR 72    // s_V row stride (bf16)
#define WSTR 104   // ws W2T row stride (bf16)
#define HSTR 104   // h1 row stride (bf16); cols 80..95 zero pad

// d_ws layout (bytes):
#define WS_A    0        // A[h][f]  bf16 [80][64]
#define WS_C    10240    // C[h][f]  bf16 [80][64]
#define WS_W2T  20480    // W2Tp[g][h] bf16 [48][104]
#define WS_ACT  30464    // W1acT[h][f] f32 [80][64]

typedef __bf16 bf16x8 __attribute__((ext_vector_type(8)));
typedef float  f32x4  __attribute__((ext_vector_type(4)));

__device__ __forceinline__ float sigmoidf_(float x) {
    return __builtin_amdgcn_rcpf(1.0f + __expf(-x));
}

// ---------- prep: block-invariant weight transforms ----------
__global__ __launch_bounds__(256)
void prep_kernel(const float* __restrict__ W1, const float* __restrict__ W2,
                 void* __restrict__ ws)
{
    __bf16* A    = (__bf16*)((char*)ws + WS_A);
    __bf16* C    = (__bf16*)((char*)ws + WS_C);
    __bf16* W2Tp = (__bf16*)((char*)ws + WS_W2T);
    float*  acT  = (float*)((char*)ws + WS_ACT);
    const int e0 = blockIdx.x * 256 + threadIdx.x;

    for (int e = e0; e < H1_ * D_; e += 2048) {
        int h = e >> 6, f = e & 63;
        float wb = W1[(64  + f) * H1_ + h];
        float wc = W1[(128 + f) * H1_ + h];
        float wd = W1[(192 + f) * H1_ + h];
        float wa = W1[f * H1_ + h];
        A[e]   = (__bf16)(wb - wc);
        C[e]   = (__bf16)wd;
        acT[e] = wa + wc;
    }
    for (int e = e0; e < 48 * WSTR; e += 2048) {
        int g = e / WSTR, h = e - g * WSTR;
        W2Tp[e] = (g < H2_ && h < H1_) ? (__bf16)W2[h * H2_ + g] : (__bf16)0.0f;
    }
}

// ---------- main: one batch per wave, zero barriers ----------
__global__ __launch_bounds__(256, 2)
void attn_din9(const float* __restrict__ query,
               const float* __restrict__ key,
               const int*   __restrict__ mask,
               const float* __restrict__ b1,
               const float* __restrict__ b2,
               const float* __restrict__ W3,
               const float* __restrict__ b3,
               const void*  __restrict__ ws,
               float* __restrict__ out)
{
    __shared__ __align__(16) __bf16 s_V[4][H1_ * VSTR];    // 46080 B (per-wave)
    __shared__ __align__(16) __bf16 s_h1[4][16 * HSTR];    // 13312 B (per-wave)
    __shared__ float  s_scf[4][208];                        //  3328 B
    __shared__ float  s_q[4][D_];                           //  1024 B
    __shared__ float  s_base[4][H1_];                       //  1280 B
    // total 65024 B <= 64 KiB -> 2 blocks/CU

    const int tid  = threadIdx.x;
    const int lane = tid & 63;
    const int w    = tid >> 6;
    const int c16  = lane & 15;
    const int g16  = lane >> 4;
    const int b    = blockIdx.x * 4 + w;       // wave-private batch

    const int   mv     = mask[b];
    const int   ntiles = (mv + 15) >> 4;
    const float b3v    = b3[0];
    const float* kb = key + (size_t)b * T_ * D_;

    const __bf16* wsA   = (const __bf16*)((const char*)ws + WS_A);
    const __bf16* wsC   = (const __bf16*)((const char*)ws + WS_C);
    const __bf16* wsW2T = (const __bf16*)((const char*)ws + WS_W2T);
    const float*  wsacT = (const float*) ((const char*)ws + WS_ACT);

    // ---- issue q load + tile-0 key load early (latency hides under staging) ----
    float qv = query[b * D_ + lane];
    float4 u0, u1, u2, u3;
    {
        int tr = c16;                           // tile 0 rows (always live: mv>=1)
        const float* kr = kb + (size_t)tr * D_ + g16 * 8;
        u0 = *(const float4*)(kr);
        u1 = *(const float4*)(kr + 4);
        u2 = *(const float4*)(kr + 32);
        u3 = *(const float4*)(kr + 36);
    }

    // ---- score buffer init (208 slots, wave-private) ----
    s_scf[w][lane]       = -1e30f;
    s_scf[w][64 + lane]  = -1e30f;
    s_scf[w][128 + lane] = -1e30f;
    if (lane < 16) s_scf[w][192 + lane] = -1e30f;

    // ---- W2T fragments into registers (L2-resident ws) ----
    bf16x8 bw[3][3];
    #pragma unroll
    for (int nt = 0; nt < 3; ++nt)
        #pragma unroll
        for (int ks = 0; ks < 3; ++ks)
            bw[nt][ks] = *(const bf16x8*)&wsW2T[(nt * 16 + c16) * WSTR + ks * 32 + g16 * 8];

    float b2c[3], w3c[3];
    #pragma unroll
    for (int nt = 0; nt < 3; ++nt) {
        int g = nt * 16 + c16;
        b2c[nt] = (g < H2_) ? b2[g] : 0.0f;
        w3c[nt] = (g < H2_) ? W3[g] : 0.0f;
    }

    // ---- q into wave-private LDS ----
    s_q[w][lane] = qv;

    // ---- V = A + q*C (wave-private, 640 chunks / 64 lanes) ----
    #pragma unroll
    for (int i = 0; i < 10; ++i) {
        int e = lane + 64 * i;
        int h = e >> 3, f8 = e & 7;
        bf16x8 a8 = *(const bf16x8*)&wsA[e * 8];
        bf16x8 c8 = *(const bf16x8*)&wsC[e * 8];
        f32x4 q0 = *(const f32x4*)&s_q[w][f8 * 8];
        f32x4 q1 = *(const f32x4*)&s_q[w][f8 * 8 + 4];
        bf16x8 v8;
        v8[0] = (__bf16)((float)a8[0] + q0[0] * (float)c8[0]);
        v8[1] = (__bf16)((float)a8[1] + q0[1] * (float)c8[1]);
        v8[2] = (__bf16)((float)a8[2] + q0[2] * (float)c8[2]);
        v8[3] = (__bf16)((float)a8[3] + q0[3] * (float)c8[3]);
        v8[4] = (__bf16)((float)a8[4] + q1[0] * (float)c8[4]);
        v8[5] = (__bf16)((float)a8[5] + q1[1] * (float)c8[5]);
        v8[6] = (__bf16)((float)a8[6] + q1[2] * (float)c8[6]);
        v8[7] = (__bf16)((float)a8[7] + q1[3] * (float)c8[7]);
        *(bf16x8*)&s_V[w][h * VSTR + f8 * 8] = v8;
    }

    // ---- base[h] = b1[h] + q.(W1a+W1c) (lane h; lanes<16 also h+64) ----
    {
        float a0 = b1[lane], a1 = 0.0f, a2 = 0.0f, a3 = 0.0f;
        const f32x4* row = (const f32x4*)&wsacT[lane * D_];
        #pragma unroll
        for (int f4 = 0; f4 < 16; ++f4) {
            f32x4 v  = row[f4];
            f32x4 q4 = *(const f32x4*)&s_q[w][f4 * 4];
            a0 = fmaf(q4[0], v[0], a0);
            a1 = fmaf(q4[1], v[1], a1);
            a2 = fmaf(q4[2], v[2], a2);
            a3 = fmaf(q4[3], v[3], a3);
        }
        s_base[w][lane] = (a0 + a1) + (a2 + a3);
    }
    if (lane < 16) {
        int h = 64 + lane;
        float a0 = b1[h], a1 = 0.0f, a2 = 0.0f, a3 = 0.0f;
        const f32x4* row = (const f32x4*)&wsacT[h * D_];
        #pragma unroll
        for (int f4 = 0; f4 < 16; ++f4) {
            f32x4 v  = row[f4];
            f32x4 q4 = *(const f32x4*)&s_q[w][f4 * 4];
            a0 = fmaf(q4[0], v[0], a0);
            a1 = fmaf(q4[1], v[1], a1);
            a2 = fmaf(q4[2], v[2], a2);
            a3 = fmaf(q4[3], v[3], a3);
        }
        s_base[w][h] = (a0 + a1) + (a2 + a3);
    }

    // ---- zero h1 pad cols 80..95 (wave-private, once) ----
    {
        int row = lane & 15, c0 = 80 + (lane >> 4) * 4;
        *(uint2*)&s_h1[w][row * HSTR + c0] = make_uint2(0u, 0u);
    }

    // ---- hoist base_c (same-wave LDS, compiler inserts lgkm wait) ----
    float base_c[5];
    #pragma unroll
    for (int nt = 0; nt < 5; ++nt) base_c[nt] = s_base[w][nt * 16 + c16];
    __bf16* myh = &s_h1[w][0];

    // ---------------- main loop: this wave does ALL its batch's tiles ----------------
    for (int tt = 0; tt < ntiles; ++tt) {
        bf16x8 af0, af1;
        af0[0] = (__bf16)u0.x; af0[1] = (__bf16)u0.y; af0[2] = (__bf16)u0.z; af0[3] = (__bf16)u0.w;
        af0[4] = (__bf16)u1.x; af0[5] = (__bf16)u1.y; af0[6] = (__bf16)u1.z; af0[7] = (__bf16)u1.w;
        af1[0] = (__bf16)u2.x; af1[1] = (__bf16)u2.y; af1[2] = (__bf16)u2.z; af1[3] = (__bf16)u2.w;
        af1[4] = (__bf16)u3.x; af1[5] = (__bf16)u3.y; af1[6] = (__bf16)u3.z; af1[7] = (__bf16)u3.w;

        // T14 prefetch next tile
        if (tt + 1 < ntiles) {
            int tr = (tt + 1) * 16 + c16;
            const float* kr = kb + (size_t)((tr < T_) ? tr : (T_ - 1)) * D_ + g16 * 8;
            u0 = *(const float4*)(kr);
            u1 = *(const float4*)(kr + 4);
            u2 = *(const float4*)(kr + 32);
            u3 = *(const float4*)(kr + 36);
        }

        // layer 1 -> sigmoid -> h1 (wave-private LDS transpose)
        #pragma unroll
        for (int nt = 0; nt < 5; ++nt) {
            float bb = base_c[nt];
            f32x4 c = { bb, bb, bb, bb };
            bf16x8 bv0 = *(const bf16x8*)&s_V[w][(nt * 16 + c16) * VSTR + g16 * 8];
            bf16x8 bv1 = *(const bf16x8*)&s_V[w][(nt * 16 + c16) * VSTR + 32 + g16 * 8];
            c = __builtin_amdgcn_mfma_f32_16x16x32_bf16(af0, bv0, c, 0, 0, 0);
            c = __builtin_amdgcn_mfma_f32_16x16x32_bf16(af1, bv1, c, 0, 0, 0);
            #pragma unroll
            for (int r = 0; r < 4; ++r)
                myh[(g16 * 4 + r) * HSTR + nt * 16 + c16] = (__bf16)sigmoidf_(c[r]);
        }

        // layer 2
        bf16x8 a2_0 = *(const bf16x8*)&myh[c16 * HSTR + g16 * 8];
        bf16x8 a2_1 = *(const bf16x8*)&myh[c16 * HSTR + 32 + g16 * 8];
        bf16x8 a2_2 = *(const bf16x8*)&myh[c16 * HSTR + 64 + g16 * 8];
        f32x4 acc2[3];
        #pragma unroll
        for (int nt = 0; nt < 3; ++nt) {
            float bb = b2c[nt];
            f32x4 c = { bb, bb, bb, bb };
            c = __builtin_amdgcn_mfma_f32_16x16x32_bf16(a2_0, bw[nt][0], c, 0, 0, 0);
            c = __builtin_amdgcn_mfma_f32_16x16x32_bf16(a2_1, bw[nt][1], c, 0, 0, 0);
            c = __builtin_amdgcn_mfma_f32_16x16x32_bf16(a2_2, bw[nt][2], c, 0, 0, 0);
            acc2[nt] = c;
        }

        // layer 3 + masked score (reduce over c16 lanes)
        const int tb = tt * 16;
        #pragma unroll
        for (int r = 0; r < 4; ++r) {
            float partial = sigmoidf_(acc2[0][r]) * w3c[0]
                          + sigmoidf_(acc2[1][r]) * w3c[1]
                          + sigmoidf_(acc2[2][r]) * w3c[2];
            partial += __shfl_xor(partial, 1);
            partial += __shfl_xor(partial, 2);
            partial += __shfl_xor(partial, 4);
            partial += __shfl_xor(partial, 8);
            int t = tb + g16 * 4 + r;
            if (c16 == 0 && t < mv)
                s_scf[w][t] = (partial + b3v) * 0.125f;
        }
    }
    asm volatile("s_waitcnt lgkmcnt(0)" ::: "memory");

    // ---------------- in-wave softmax over 208 slots ----------------
    float s0 = s_scf[w][lane];
    float s1 = s_scf[w][64 + lane];
    float s2 = s_scf[w][128 + lane];
    float s3 = (lane < 16) ? s_scf[w][192 + lane] : -1e30f;
    float m = fmaxf(fmaxf(s0, s1), fmaxf(s2, s3));
    #pragma unroll
    for (int off = 32; off >= 1; off >>= 1) m = fmaxf(m, __shfl_xor(m, off));
    float p0 = __expf(s0 - m), p1 = __expf(s1 - m);
    float p2 = __expf(s2 - m), p3 = (lane < 16) ? __expf(s3 - m) : 0.0f;
    float ps = (p0 + p1) + (p2 + p3);
    #pragma unroll
    for (int off = 32; off >= 1; off >>= 1) ps += __shfl_xor(ps, off);
    float inv_total = __builtin_amdgcn_rcpf(ps);
    s_scf[w][lane]       = p0;
    s_scf[w][64 + lane]  = p1;
    s_scf[w][128 + lane] = p2;
    if (lane < 16) s_scf[w][192 + lane] = p3;
    asm volatile("s_waitcnt lgkmcnt(0)" ::: "memory");

    // ---------------- in-wave weighted sum: out[b][d=lane] ----------------
    float a0 = 0.0f, a1 = 0.0f, a2s = 0.0f, a3s = 0.0f;
    const float* ksc = &s_scf[w][0];
    int t = 0;
    for (; t + 4 <= mv; t += 4) {
        a0  = fmaf(ksc[t],     kb[(t)     * D_ + lane], a0);
        a1  = fmaf(ksc[t + 1], kb[(t + 1) * D_ + lane], a1);
        a2s = fmaf(ksc[t + 2], kb[(t + 2) * D_ + lane], a2s);
        a3s = fmaf(ksc[t + 3], kb[(t + 3) * D_ + lane], a3s);
    }
    for (; t < mv; ++t)
        a0 = fmaf(ksc[t], kb[t * D_ + lane], a0);
    out[b * D_ + lane] = ((a0 + a1) + (a2s + a3s)) * inv_total;
}

extern "C" void kernel_launch(void* const* d_in, const int* in_sizes, int n_in,
                              void* d_out, int out_size, void* d_ws, size_t ws_size,
                              hipStream_t stream)
{
    const float* query = (const float*)d_in[0];
    const float* key   = (const float*)d_in[1];
    const int*   mask  = (const int*)  d_in[2];
    const float* W1    = (const float*)d_in[3];
    const float* b1    = (const float*)d_in[4];
    const float* W2    = (const float*)d_in[5];
    const float* b2    = (const float*)d_in[6];
    const float* W3    = (const float*)d_in[7];
    const float* b3    = (const float*)d_in[8];
    float* out = (float*)d_out;

    prep_kernel<<<8, 256, 0, stream>>>(W1, W2, d_ws);
    attn_din9<<<512, 256, 0, stream>>>(query, key, mask, b1, b2, W3, b3, d_ws, out);
}